// Round 7
// baseline (101.634 us; speedup 1.0000x reference)
//
#include <hip/hip_runtime.h>
#include <cmath>

// x,y: (16,3,512,512) f32. Fused separable-Gaussian SSIM, scalar mean output.
// Row-streaming pairs with 1-pair-deep global prefetch, 12-slot static ring,
// shared products in v-conv, b128 sliding-window h-conv on 21KB LDS row-pair.
constexpr int IMG_H = 512;
constexpr int IMG_W = 512;
constexpr int PLANES = 48;
constexpr int R_OUT = 8;                // output rows per block (4 pairs)
constexpr int BANDS = IMG_H / R_OUT;    // 64
constexpr int PSTR = 524;               // padded row: col c stored at p = c+6; p in [0,524)
constexpr long long TOTAL_PIX = (long long)PLANES * IMG_H * IMG_W;

struct GWin { float g[11]; };

__global__ __launch_bounds__(256)
void ssim_pf_kernel(const float* __restrict__ x,
                    const float* __restrict__ y,
                    double* __restrict__ accum,
                    GWin win)
{
    __shared__ __align__(16) float hbuf[2][5][PSTR];  // v-conv'd row pair, 5 fields
    __shared__ float wsum[4];

    const int tid   = threadIdx.x;
    const int band  = blockIdx.x & (BANDS - 1);
    const int plane = blockIdx.x >> 6;
    const int r0    = band * R_OUT;
    const int c0    = tid * 2;           // v-pass: 2 columns per thread

    const float* __restrict__ xp = x + (size_t)plane * (IMG_H * IMG_W);
    const float* __restrict__ yp = y + (size_t)plane * (IMG_H * IMG_W);

    // zero horizontal halo slots once: p in [0,6) and [518,524), 2 rows x 5 fields
    if (tid < 120) {
        int w  = tid % 12;
        int bf = tid / 12;                  // 0..9 -> row bf/5, field bf%5
        int p  = (w < 6) ? w : (512 + w);   // 0..5, 518..523
        hbuf[bf / 5][bf % 5][p] = 0.f;
    }
    // (ordered before any h-read by the first in-loop __syncthreads)

    // 12-slot register ring of x,y rows; all indices compile-time static
    float2 xr[12], yr[12];

    auto load2 = [&](const float* __restrict__ base, int i) -> float2 {
        int gr = r0 - 5 + i;               // input row for ring position i
        if ((unsigned)gr < (unsigned)IMG_H)
            return *(const float2*)(base + (size_t)gr * IMG_W + c0);
        return make_float2(0.f, 0.f);
    };

#pragma unroll
    for (int i = 0; i < 10; ++i) {
        xr[i] = load2(xp, i);
        yr[i] = load2(yp, i);
    }
    // prefetch registers hold rows for ring slots 10,11 of the CURRENT pair
    float2 pfx0 = load2(xp, 10), pfy0 = load2(yp, 10);
    float2 pfx1 = load2(xp, 11), pfy1 = load2(yp, 11);

    float lsum = 0.f;

#pragma unroll 1
    for (int p = 0; p < 4; ++p) {
        // commit prefetched rows into the ring
        xr[10] = pfx0;  yr[10] = pfy0;
        xr[11] = pfx1;  yr[11] = pfy1;

        // issue next pair's loads NOW — consumed only at the next commit,
        // hidden under v-conv + barrier + h-pass (~1k cycles)
        if (p < 3) {
            const int ib = 2 * p + 12;
            pfx0 = load2(xp, ib);      pfy0 = load2(yp, ib);
            pfx1 = load2(xp, ib + 1);  pfy1 = load2(yp, ib + 1);
        }

        // vertical 11-tap conv of rows 2p (slots 0..10) and 2p+1 (slots 1..11),
        // products computed once per input row
        {
            float2 vx[2], vy[2], vxx[2], vyy[2], vxy[2];
#pragma unroll
            for (int r = 0; r < 2; ++r)
                vx[r] = vy[r] = vxx[r] = vyy[r] = vxy[r] = make_float2(0.f, 0.f);
#pragma unroll
            for (int k = 0; k < 12; ++k) {
                const float2 xv = xr[k], yv = yr[k];
                const float2 pxx = make_float2(xv.x * xv.x, xv.y * xv.y);
                const float2 pyy = make_float2(yv.x * yv.x, yv.y * yv.y);
                const float2 pxy = make_float2(xv.x * yv.x, xv.y * yv.y);
                if (k < 11) {
                    const float g = win.g[k];
                    vx[0].x  += g * xv.x;   vx[0].y  += g * xv.y;
                    vy[0].x  += g * yv.x;   vy[0].y  += g * yv.y;
                    vxx[0].x += g * pxx.x;  vxx[0].y += g * pxx.y;
                    vyy[0].x += g * pyy.x;  vyy[0].y += g * pyy.y;
                    vxy[0].x += g * pxy.x;  vxy[0].y += g * pxy.y;
                }
                if (k > 0) {
                    const float g = win.g[k - 1];
                    vx[1].x  += g * xv.x;   vx[1].y  += g * xv.y;
                    vy[1].x  += g * yv.x;   vy[1].y  += g * yv.y;
                    vxx[1].x += g * pxx.x;  vxx[1].y += g * pxx.y;
                    vyy[1].x += g * pyy.x;  vyy[1].y += g * pyy.y;
                    vxy[1].x += g * pxy.x;  vxy[1].y += g * pxy.y;
                }
            }
#pragma unroll
            for (int r = 0; r < 2; ++r) {
                float* hb = &hbuf[r][0][0];
                *(float2*)&hb[0 * PSTR + 6 + c0] = vx[r];
                *(float2*)&hb[1 * PSTR + 6 + c0] = vy[r];
                *(float2*)&hb[2 * PSTR + 6 + c0] = vxx[r];
                *(float2*)&hb[3 * PSTR + 6 + c0] = vyy[r];
                *(float2*)&hb[4 * PSTR + 6 + c0] = vxy[r];
            }
        }

        __syncthreads();

        // horizontal 11-tap conv: rw = tid>>7 (row), q = tid&127 (cols 4q..4q+3)
        {
            const int rw = tid >> 7;
            const int q  = tid & 127;
            float m[5][4];
#pragma unroll
            for (int f = 0; f < 5; ++f) {
                const float4* rowv = (const float4*)&hbuf[rw][f][0];
                float4 a = rowv[q];
                float4 b = rowv[q + 1];
                float4 c = rowv[q + 2];
                float4 d = rowv[q + 3];
                float w16[16] = { a.x, a.y, a.z, a.w,  b.x, b.y, b.z, b.w,
                                  c.x, c.y, c.z, c.w,  d.x, d.y, d.z, d.w };
#pragma unroll
                for (int j = 0; j < 4; ++j) {
                    float s = 0.f;
#pragma unroll
                    for (int k = 0; k < 11; ++k) s += win.g[k] * w16[j + k + 1];
                    m[f][j] = s;
                }
            }
#pragma unroll
            for (int u = 0; u < 4; ++u) {
                float mx  = m[0][u];
                float my  = m[1][u];
                float mxx = m[2][u];
                float myy = m[3][u];
                float mxy = m[4][u];
                float mu_x_sq = mx * mx;
                float mu_y_sq = my * my;
                float mu_xy   = mx * my;
                float sig_x  = mxx - mu_x_sq;
                float sig_y  = myy - mu_y_sq;
                float sig_xy = mxy - mu_xy;
                const float C1 = 0.01f * 0.01f;
                const float C2 = 0.03f * 0.03f;
                float n = (2.f * mu_xy + C1) * (2.f * sig_xy + C2);
                float d = (mu_x_sq + mu_y_sq + C1) * (sig_x + sig_y + C2);
                lsum += n / (d + 1e-8f);
            }
        }

        __syncthreads();   // protect hbuf before next pair's writes

        // shift ring down by 2 (static indices)
#pragma unroll
        for (int k = 0; k < 10; ++k) { xr[k] = xr[k + 2]; yr[k] = yr[k + 2]; }
    }

    // block reduction
#pragma unroll
    for (int off = 32; off; off >>= 1) lsum += __shfl_down(lsum, off);
    if ((tid & 63) == 0) wsum[tid >> 6] = lsum;
    __syncthreads();
    if (tid == 0)
        atomicAdd(accum, (double)(wsum[0] + wsum[1] + wsum[2] + wsum[3]));
}

__global__ void ssim_finalize_kernel(const double* __restrict__ accum,
                                     float* __restrict__ out)
{
    out[0] = (float)(accum[0] / (double)TOTAL_PIX);
}

extern "C" void kernel_launch(void* const* d_in, const int* in_sizes, int n_in,
                              void* d_out, int out_size, void* d_ws, size_t ws_size,
                              hipStream_t stream) {
    const float* x = (const float*)d_in[0];
    const float* y = (const float*)d_in[1];
    float* out = (float*)d_out;
    double* accum = (double*)d_ws;

    GWin win;
    {
        double g[11], s = 0.0;
        for (int i = 0; i < 11; ++i) {
            double d = (double)i - 5.0;
            g[i] = std::exp(-(d * d) / (2.0 * 1.5 * 1.5));
            s += g[i];
        }
        for (int i = 0; i < 11; ++i) win.g[i] = (float)(g[i] / s);
    }

    hipMemsetAsync(d_ws, 0, sizeof(double), stream);

    const int nblocks = PLANES * BANDS;  // 3072
    ssim_pf_kernel<<<nblocks, 256, 0, stream>>>(x, y, accum, win);
    ssim_finalize_kernel<<<1, 1, 0, stream>>>(accum, out);
}

// Round 8
// 101.521 us; speedup vs baseline: 1.0011x; 1.0011x over previous
//
#include <hip/hip_runtime.h>
#include <cmath>

// x,y: (16,3,512,512) f32. Fused separable-Gaussian SSIM, scalar mean output.
// Row-streaming pairs, 12-slot static ring, shared products in v-conv,
// h-conv via 8x ds_read_b64 sliding windows (4-way bank alias, ~1.6x) on a
// 21KB LDS row-pair. Two barriers/iter; 1-pair-deep global prefetch.
constexpr int IMG_H = 512;
constexpr int IMG_W = 512;
constexpr int PLANES = 48;
constexpr int R_OUT = 8;                // output rows per block (4 pairs)
constexpr int BANDS = IMG_H / R_OUT;    // 64
constexpr int PSTR = 524;               // col c stored at p = c+6; p in [0,524)
constexpr long long TOTAL_PIX = (long long)PLANES * IMG_H * IMG_W;

struct GWin { float g[11]; };

__global__ __launch_bounds__(256)
void ssim_b64_kernel(const float* __restrict__ x,
                     const float* __restrict__ y,
                     double* __restrict__ accum,
                     GWin win)
{
    __shared__ __align__(16) float hbuf[2][5][PSTR];  // v-conv'd row pair, 5 fields
    __shared__ float wsum[4];

    const int tid   = threadIdx.x;
    const int band  = blockIdx.x & (BANDS - 1);
    const int plane = blockIdx.x >> 6;
    const int r0    = band * R_OUT;
    const int c0    = tid * 2;           // v-pass: 2 columns per thread

    const float* __restrict__ xp = x + (size_t)plane * (IMG_H * IMG_W);
    const float* __restrict__ yp = y + (size_t)plane * (IMG_H * IMG_W);

    // zero horizontal halo slots once: p in [0,6) and [518,524), 2 rows x 5 fields
    if (tid < 120) {
        int w  = tid % 12;
        int bf = tid / 12;                  // 0..9 -> row bf/5, field bf%5
        int p  = (w < 6) ? w : (512 + w);   // 0..5, 518..523
        hbuf[bf / 5][bf % 5][p] = 0.f;
    }
    // (ordered before any h-read by the first in-loop __syncthreads)

    // 12-slot register ring of x,y rows; all indices compile-time static
    float2 xr[12], yr[12];

    auto load2 = [&](const float* __restrict__ base, int i) -> float2 {
        int gr = r0 - 5 + i;               // input row for ring position i
        if ((unsigned)gr < (unsigned)IMG_H)
            return *(const float2*)(base + (size_t)gr * IMG_W + c0);
        return make_float2(0.f, 0.f);
    };

#pragma unroll
    for (int i = 0; i < 10; ++i) {
        xr[i] = load2(xp, i);
        yr[i] = load2(yp, i);
    }
    // prefetch registers hold rows for ring slots 10,11 of the CURRENT pair
    float2 pfx0 = load2(xp, 10), pfy0 = load2(yp, 10);
    float2 pfx1 = load2(xp, 11), pfy1 = load2(yp, 11);

    float lsum = 0.f;

#pragma unroll 1
    for (int p = 0; p < 4; ++p) {
        // commit prefetched rows into the ring
        xr[10] = pfx0;  yr[10] = pfy0;
        xr[11] = pfx1;  yr[11] = pfy1;

        // issue next pair's loads NOW — consumed at next commit (~1k cyc away)
        if (p < 3) {
            const int ib = 2 * p + 12;
            pfx0 = load2(xp, ib);      pfy0 = load2(yp, ib);
            pfx1 = load2(xp, ib + 1);  pfy1 = load2(yp, ib + 1);
        }

        // vertical 11-tap conv of rows 2p (slots 0..10) and 2p+1 (slots 1..11),
        // products computed once per input row
        {
            float2 vx[2], vy[2], vxx[2], vyy[2], vxy[2];
#pragma unroll
            for (int r = 0; r < 2; ++r)
                vx[r] = vy[r] = vxx[r] = vyy[r] = vxy[r] = make_float2(0.f, 0.f);
#pragma unroll
            for (int k = 0; k < 12; ++k) {
                const float2 xv = xr[k], yv = yr[k];
                const float2 pxx = make_float2(xv.x * xv.x, xv.y * xv.y);
                const float2 pyy = make_float2(yv.x * yv.x, yv.y * yv.y);
                const float2 pxy = make_float2(xv.x * yv.x, xv.y * yv.y);
                if (k < 11) {
                    const float g = win.g[k];
                    vx[0].x  += g * xv.x;   vx[0].y  += g * xv.y;
                    vy[0].x  += g * yv.x;   vy[0].y  += g * yv.y;
                    vxx[0].x += g * pxx.x;  vxx[0].y += g * pxx.y;
                    vyy[0].x += g * pyy.x;  vyy[0].y += g * pyy.y;
                    vxy[0].x += g * pxy.x;  vxy[0].y += g * pxy.y;
                }
                if (k > 0) {
                    const float g = win.g[k - 1];
                    vx[1].x  += g * xv.x;   vx[1].y  += g * xv.y;
                    vy[1].x  += g * yv.x;   vy[1].y  += g * yv.y;
                    vxx[1].x += g * pxx.x;  vxx[1].y += g * pxx.y;
                    vyy[1].x += g * pyy.x;  vyy[1].y += g * pyy.y;
                    vxy[1].x += g * pxy.x;  vxy[1].y += g * pxy.y;
                }
            }
#pragma unroll
            for (int r = 0; r < 2; ++r) {
                float* hb = &hbuf[r][0][0];
                *(float2*)&hb[0 * PSTR + 6 + c0] = vx[r];
                *(float2*)&hb[1 * PSTR + 6 + c0] = vy[r];
                *(float2*)&hb[2 * PSTR + 6 + c0] = vxx[r];
                *(float2*)&hb[3 * PSTR + 6 + c0] = vyy[r];
                *(float2*)&hb[4 * PSTR + 6 + c0] = vxy[r];
            }
        }

        __syncthreads();

        // horizontal 11-tap conv: rw = tid>>7 (row), q = tid&127 (cols 4q..4q+3)
        // window: 8x float2 (b64) from even base p=4q -> floats cover c in
        // [4q-6, 4q+10); taps use w[1..14]. 4-way bank alias (~1.6x), no b128.
        {
            const int rw = tid >> 7;
            const int q  = tid & 127;
            float m[5][4];
#pragma unroll
            for (int f = 0; f < 5; ++f) {
                const float2* rowv = (const float2*)&hbuf[rw][f][4 * q];
                float w16[16];
#pragma unroll
                for (int j = 0; j < 8; ++j) {
                    float2 v = rowv[j];
                    w16[2 * j]     = v.x;
                    w16[2 * j + 1] = v.y;
                }
#pragma unroll
                for (int j = 0; j < 4; ++j) {
                    float s = 0.f;
#pragma unroll
                    for (int k = 0; k < 11; ++k) s += win.g[k] * w16[j + k + 1];
                    m[f][j] = s;
                }
            }
#pragma unroll
            for (int u = 0; u < 4; ++u) {
                float mx  = m[0][u];
                float my  = m[1][u];
                float mxx = m[2][u];
                float myy = m[3][u];
                float mxy = m[4][u];
                float mu_x_sq = mx * mx;
                float mu_y_sq = my * my;
                float mu_xy   = mx * my;
                float sig_x  = mxx - mu_x_sq;
                float sig_y  = myy - mu_y_sq;
                float sig_xy = mxy - mu_xy;
                const float C1 = 0.01f * 0.01f;
                const float C2 = 0.03f * 0.03f;
                float n = (2.f * mu_xy + C1) * (2.f * sig_xy + C2);
                float d = (mu_x_sq + mu_y_sq + C1) * (sig_x + sig_y + C2);
                lsum += n / (d + 1e-8f);
            }
        }

        __syncthreads();   // protect hbuf before next pair's writes

        // shift ring down by 2 (static indices)
#pragma unroll
        for (int k = 0; k < 10; ++k) { xr[k] = xr[k + 2]; yr[k] = yr[k + 2]; }
    }

    // block reduction
#pragma unroll
    for (int off = 32; off; off >>= 1) lsum += __shfl_down(lsum, off);
    if ((tid & 63) == 0) wsum[tid >> 6] = lsum;
    __syncthreads();
    if (tid == 0)
        atomicAdd(accum, (double)(wsum[0] + wsum[1] + wsum[2] + wsum[3]));
}

__global__ void ssim_finalize_kernel(const double* __restrict__ accum,
                                     float* __restrict__ out)
{
    out[0] = (float)(accum[0] / (double)TOTAL_PIX);
}

extern "C" void kernel_launch(void* const* d_in, const int* in_sizes, int n_in,
                              void* d_out, int out_size, void* d_ws, size_t ws_size,
                              hipStream_t stream) {
    const float* x = (const float*)d_in[0];
    const float* y = (const float*)d_in[1];
    float* out = (float*)d_out;
    double* accum = (double*)d_ws;

    GWin win;
    {
        double g[11], s = 0.0;
        for (int i = 0; i < 11; ++i) {
            double d = (double)i - 5.0;
            g[i] = std::exp(-(d * d) / (2.0 * 1.5 * 1.5));
            s += g[i];
        }
        for (int i = 0; i < 11; ++i) win.g[i] = (float)(g[i] / s);
    }

    hipMemsetAsync(d_ws, 0, sizeof(double), stream);

    const int nblocks = PLANES * BANDS;  // 3072
    ssim_b64_kernel<<<nblocks, 256, 0, stream>>>(x, y, accum, win);
    ssim_finalize_kernel<<<1, 1, 0, stream>>>(accum, out);
}

// Round 9
// 75.224 us; speedup vs baseline: 1.3511x; 1.3496x over previous
//
#include <hip/hip_runtime.h>
#include <cmath>

// x,y: (16,3,512,512) f32. Fused separable-Gaussian SSIM, scalar mean output.
// Quad-row structure: per 4 output rows, stream 14 input rows through registers
// (products + v-conv accumulate, no ring), store 5 v-conv'd fields to a bank-
// swizzled LDS buffer, h-conv with 8 cols/thread (24-float window, 6x b128 at
// the 8-bank-cycle floor). 2 barriers per quad, 4 per block.
constexpr int IMG_H = 512;
constexpr int IMG_W = 512;
constexpr int PLANES = 48;
constexpr int R_OUT = 8;                 // output rows per block (2 quads)
constexpr int BANDS = IMG_H / R_OUT;     // 64
constexpr int PSTR = 528;                // field-row dwords; col c at p = c+8
constexpr long long TOTAL_PIX = (long long)PLANES * IMG_H * IMG_W;

struct GWin { float g[11]; };

// XOR bank swizzle on the within-field-row dword offset. Block-level form:
// blk -> blk ^ ((blk>>3)&7). Dword-level swzd(4*blk+i) == 4*swzb(blk)+i, so
// float2 writes (even p) and float4 reads use consistent physical locations.
__device__ __forceinline__ int swzd(int p) { return p ^ (((p >> 5) & 7) << 2); }

__global__ __launch_bounds__(256)
void ssim_quad_kernel(const float* __restrict__ x,
                      const float* __restrict__ y,
                      double* __restrict__ accum,
                      GWin win)
{
    __shared__ __align__(16) float hbuf[4][5][PSTR];   // 42.24 KB
    __shared__ float wsum[4];

    const int tid   = threadIdx.x;
    const int band  = blockIdx.x & (BANDS - 1);
    const int plane = blockIdx.x >> 6;
    const int r0    = band * R_OUT;
    const int c0    = tid * 2;            // v-pass: 2 columns per thread

    const float* __restrict__ xp = x + (size_t)plane * (IMG_H * IMG_W);
    const float* __restrict__ yp = y + (size_t)plane * (IMG_H * IMG_W);

    // zero halo cols: p in [0,8) (cols < 0) and [520,528) (cols >= 512),
    // for all 4 rows x 5 fields (store to swizzled physical slots)
    for (int i = tid; i < 320; i += 256) {
        int rf = i >> 4, w = i & 15;
        int p  = (w < 8) ? w : (512 + w);       // 0..7, 520..527
        (&hbuf[0][0][0])[rf * PSTR + swzd(p)] = 0.f;
    }
    // (ordered before any h-read by the first __syncthreads)

    auto load2 = [&](const float* __restrict__ base, int gr) -> float2 {
        if ((unsigned)gr < (unsigned)IMG_H)
            return *(const float2*)(base + (size_t)gr * IMG_W + c0);
        return make_float2(0.f, 0.f);
    };

    const int pws = swzd(2 * tid + 8);    // v-write physical offset (even -> pair-contiguous)
    float lsum = 0.f;

#pragma unroll 1
    for (int q = 0; q < 2; ++q) {
        const int rq = r0 + 4 * q;        // first output row of this quad

        // ---- vertical 11-tap conv of {x,y,xx,yy,xy} for 4 rows, streaming ----
        float2 acc[4][5];
#pragma unroll
        for (int j = 0; j < 4; ++j)
#pragma unroll
            for (int f = 0; f < 5; ++f) acc[j][f] = make_float2(0.f, 0.f);

#pragma unroll
        for (int k = 0; k < 14; ++k) {
            const float2 xv = load2(xp, rq - 5 + k);
            const float2 yv = load2(yp, rq - 5 + k);
            const float2 pxx = make_float2(xv.x * xv.x, xv.y * xv.y);
            const float2 pyy = make_float2(yv.x * yv.x, yv.y * yv.y);
            const float2 pxy = make_float2(xv.x * yv.x, xv.y * yv.y);
#pragma unroll
            for (int j = 0; j < 4; ++j) {
                const int t = k - j;               // compile-time
                if (t >= 0 && t <= 10) {
                    const float g = win.g[t];
                    acc[j][0].x += g * xv.x;   acc[j][0].y += g * xv.y;
                    acc[j][1].x += g * yv.x;   acc[j][1].y += g * yv.y;
                    acc[j][2].x += g * pxx.x;  acc[j][2].y += g * pxx.y;
                    acc[j][3].x += g * pyy.x;  acc[j][3].y += g * pyy.y;
                    acc[j][4].x += g * pxy.x;  acc[j][4].y += g * pxy.y;
                }
            }
        }

#pragma unroll
        for (int j = 0; j < 4; ++j)
#pragma unroll
            for (int f = 0; f < 5; ++f)
                *(float2*)&hbuf[j][f][pws] = acc[j][f];

        __syncthreads();

        // ---- horizontal 11-tap conv: wave -> row, lane -> cols 8l..8l+7 ----
        {
            const int row = tid >> 6;
            const int l   = tid & 63;
            float m[5][8];
#pragma unroll
            for (int f = 0; f < 5; ++f) {
                const float* fr = &hbuf[row][f][0];
                float w24[24];
#pragma unroll
                for (int B = 0; B < 6; ++B) {
                    const int blk = 2 * l + B;
                    const int pb  = blk ^ ((blk >> 3) & 7);
                    const float4 v = *(const float4*)&fr[4 * pb];
                    w24[4 * B + 0] = v.x;  w24[4 * B + 1] = v.y;
                    w24[4 * B + 2] = v.z;  w24[4 * B + 3] = v.w;
                }
                // output col c = 8l+j, window floats p = c+3..c+13 -> w24[j+3+k]
#pragma unroll
                for (int j = 0; j < 8; ++j) {
                    float s = 0.f;
#pragma unroll
                    for (int k = 0; k < 11; ++k) s += win.g[k] * w24[j + 3 + k];
                    m[f][j] = s;
                }
            }

#pragma unroll
            for (int u = 0; u < 8; ++u) {
                const float mx  = m[0][u];
                const float my  = m[1][u];
                const float mxx = m[2][u];
                const float myy = m[3][u];
                const float mxy = m[4][u];
                const float mu_x_sq = mx * mx;
                const float mu_y_sq = my * my;
                const float mu_xy   = mx * my;
                const float sig_x  = mxx - mu_x_sq;
                const float sig_y  = myy - mu_y_sq;
                const float sig_xy = mxy - mu_xy;
                const float C1 = 0.01f * 0.01f;
                const float C2 = 0.03f * 0.03f;
                const float n = (2.f * mu_xy + C1) * (2.f * sig_xy + C2);
                const float d = (mu_x_sq + mu_y_sq + C1) * (sig_x + sig_y + C2);
                lsum += n / (d + 1e-8f);
            }
        }

        __syncthreads();   // protect hbuf before next quad's writes
    }

    // ---- block reduction ----
#pragma unroll
    for (int off = 32; off; off >>= 1) lsum += __shfl_down(lsum, off);
    if ((tid & 63) == 0) wsum[tid >> 6] = lsum;
    __syncthreads();
    if (tid == 0)
        atomicAdd(accum, (double)(wsum[0] + wsum[1] + wsum[2] + wsum[3]));
}

__global__ void ssim_finalize_kernel(const double* __restrict__ accum,
                                     float* __restrict__ out)
{
    out[0] = (float)(accum[0] / (double)TOTAL_PIX);
}

extern "C" void kernel_launch(void* const* d_in, const int* in_sizes, int n_in,
                              void* d_out, int out_size, void* d_ws, size_t ws_size,
                              hipStream_t stream) {
    const float* x = (const float*)d_in[0];
    const float* y = (const float*)d_in[1];
    float* out = (float*)d_out;
    double* accum = (double*)d_ws;

    GWin win;
    {
        double g[11], s = 0.0;
        for (int i = 0; i < 11; ++i) {
            double d = (double)i - 5.0;
            g[i] = std::exp(-(d * d) / (2.0 * 1.5 * 1.5));
            s += g[i];
        }
        for (int i = 0; i < 11; ++i) win.g[i] = (float)(g[i] / s);
    }

    hipMemsetAsync(d_ws, 0, sizeof(double), stream);

    const int nblocks = PLANES * BANDS;  // 3072
    ssim_quad_kernel<<<nblocks, 256, 0, stream>>>(x, y, accum, win);
    ssim_finalize_kernel<<<1, 1, 0, stream>>>(accum, out);
}

// Round 10
// 74.708 us; speedup vs baseline: 1.3604x; 1.0069x over previous
//
#include <hip/hip_runtime.h>
#include <cmath>

// x,y: (16,3,512,512) f32. Fused separable-Gaussian SSIM, scalar mean output.
// Quad-row structure, rows shared across quads in registers:
//   load 14 rows once -> quad0 v-conv -> LDS(swizzled) -> h-pass (8 cols/lane)
//   prefetch 4 rows under quad0 h-pass -> quad1 v-conv reuses 10 rows -> h-pass.
// Interior blocks skip bounds checks; division via v_rcp_f32.
constexpr int IMG_H = 512;
constexpr int IMG_W = 512;
constexpr int PLANES = 48;
constexpr int R_OUT = 8;                 // output rows per block (2 quads)
constexpr int BANDS = IMG_H / R_OUT;     // 64
constexpr int PSTR = 528;                // field-row dwords; col c at p = c+8
constexpr long long TOTAL_PIX = (long long)PLANES * IMG_H * IMG_W;

struct GWin { float g[11]; };

// XOR bank swizzle on within-field-row dword offset (same scheme as R9,
// verified: float2 writes at even p and float4 reads at 4-aligned p are
// consistent because only bits 2..4 are modified).
__device__ __forceinline__ int swzd(int p) { return p ^ (((p >> 5) & 7) << 2); }

template<bool CHK>
__device__ __forceinline__ float2 ld2(const float* __restrict__ base, int gr, int c0) {
    if (CHK && (unsigned)gr >= (unsigned)IMG_H) return make_float2(0.f, 0.f);
    return *(const float2*)(base + (size_t)gr * IMG_W + c0);
}

// horizontal 11-tap conv + SSIM over one LDS row (5 fields), 8 cols per lane
__device__ __forceinline__ float hpass8(const float (* __restrict__ fr)[PSTR],
                                        int l, const GWin& win) {
    int pb[6];
#pragma unroll
    for (int B = 0; B < 6; ++B) {
        const int blk = 2 * l + B;
        pb[B] = blk ^ ((blk >> 3) & 7);
    }
    float m[5][8];
#pragma unroll
    for (int f = 0; f < 5; ++f) {
        float w24[24];
#pragma unroll
        for (int B = 0; B < 6; ++B) {
            const float4 v = *(const float4*)&fr[f][4 * pb[B]];
            w24[4 * B + 0] = v.x;  w24[4 * B + 1] = v.y;
            w24[4 * B + 2] = v.z;  w24[4 * B + 3] = v.w;
        }
        // output col c = 8l+j; window floats p = c+3..c+13 -> w24[j+3+k]
#pragma unroll
        for (int j = 0; j < 8; ++j) {
            float s = 0.f;
#pragma unroll
            for (int k = 0; k < 11; ++k) s += win.g[k] * w24[j + 3 + k];
            m[f][j] = s;
        }
    }
    float ls = 0.f;
#pragma unroll
    for (int u = 0; u < 8; ++u) {
        const float mx  = m[0][u], my  = m[1][u];
        const float mxx = m[2][u], myy = m[3][u], mxy = m[4][u];
        const float mu_x_sq = mx * mx;
        const float mu_y_sq = my * my;
        const float mu_xy   = mx * my;
        const float sig_x  = mxx - mu_x_sq;
        const float sig_y  = myy - mu_y_sq;
        const float sig_xy = mxy - mu_xy;
        const float C1 = 0.01f * 0.01f;
        const float C2 = 0.03f * 0.03f;
        const float n = (2.f * mu_xy + C1) * (2.f * sig_xy + C2);
        const float d = (mu_x_sq + mu_y_sq + C1) * (sig_x + sig_y + C2);
        ls += n * __builtin_amdgcn_rcpf(d + 1e-8f);   // ~1 ulp; mean-safe
    }
    return ls;
}

template<bool CHK>
__device__ __forceinline__ float quad_body(const float* __restrict__ xp,
                                           const float* __restrict__ yp,
                                           int r0, int c0, int tid,
                                           float (&hbuf)[4][5][PSTR],
                                           const GWin& win)
{
    const int pws = swzd(2 * tid + 8);   // v-write physical offset (pair-contiguous)
    const int row = tid >> 6, l = tid & 63;
    float lsum = 0.f;

    // load the 14 input rows for quad 0 (10 of them reused by quad 1)
    float2 xr[14], yr[14];
#pragma unroll
    for (int i = 0; i < 14; ++i) {
        xr[i] = ld2<CHK>(xp, r0 - 5 + i, c0);
        yr[i] = ld2<CHK>(yp, r0 - 5 + i, c0);
    }

    // ---- quad 0: outputs r0..r0+3 from inputs i = 0..13 ----
    {
        float2 acc[4][5];
#pragma unroll
        for (int j = 0; j < 4; ++j)
#pragma unroll
            for (int f = 0; f < 5; ++f) acc[j][f] = make_float2(0.f, 0.f);
#pragma unroll
        for (int i = 0; i < 14; ++i) {
            const float2 xv = xr[i], yv = yr[i];
            const float2 pxx = make_float2(xv.x * xv.x, xv.y * xv.y);
            const float2 pyy = make_float2(yv.x * yv.x, yv.y * yv.y);
            const float2 pxy = make_float2(xv.x * yv.x, xv.y * yv.y);
#pragma unroll
            for (int j = 0; j < 4; ++j) {
                const int t = i - j;              // compile-time
                if (t >= 0 && t <= 10) {
                    const float g = win.g[t];
                    acc[j][0].x += g * xv.x;   acc[j][0].y += g * xv.y;
                    acc[j][1].x += g * yv.x;   acc[j][1].y += g * yv.y;
                    acc[j][2].x += g * pxx.x;  acc[j][2].y += g * pxx.y;
                    acc[j][3].x += g * pyy.x;  acc[j][3].y += g * pyy.y;
                    acc[j][4].x += g * pxy.x;  acc[j][4].y += g * pxy.y;
                }
            }
        }
#pragma unroll
        for (int j = 0; j < 4; ++j)
#pragma unroll
            for (int f = 0; f < 5; ++f)
                *(float2*)&hbuf[j][f][pws] = acc[j][f];
    }
    __syncthreads();

    // prefetch quad-1-only rows (i = 14..17) — lands under quad-0 h-pass
    float2 px[4], py[4];
#pragma unroll
    for (int i = 0; i < 4; ++i) {
        px[i] = ld2<CHK>(xp, r0 + 9 + i, c0);
        py[i] = ld2<CHK>(yp, r0 + 9 + i, c0);
    }

    lsum += hpass8(hbuf[row], l, win);
    __syncthreads();                      // protect hbuf before quad-1 writes

    // ---- quad 1: outputs r0+4..r0+7 from inputs i = 4..17 ----
    {
        float2 acc[4][5];
#pragma unroll
        for (int j = 0; j < 4; ++j)
#pragma unroll
            for (int f = 0; f < 5; ++f) acc[j][f] = make_float2(0.f, 0.f);
#pragma unroll
        for (int i = 4; i < 18; ++i) {
            const float2 xv = (i < 14) ? xr[i] : px[i - 14];   // static select
            const float2 yv = (i < 14) ? yr[i] : py[i - 14];
            const float2 pxx = make_float2(xv.x * xv.x, xv.y * xv.y);
            const float2 pyy = make_float2(yv.x * yv.x, yv.y * yv.y);
            const float2 pxy = make_float2(xv.x * yv.x, xv.y * yv.y);
#pragma unroll
            for (int j = 0; j < 4; ++j) {
                const int t = i - 4 - j;          // compile-time
                if (t >= 0 && t <= 10) {
                    const float g = win.g[t];
                    acc[j][0].x += g * xv.x;   acc[j][0].y += g * xv.y;
                    acc[j][1].x += g * yv.x;   acc[j][1].y += g * yv.y;
                    acc[j][2].x += g * pxx.x;  acc[j][2].y += g * pxx.y;
                    acc[j][3].x += g * pyy.x;  acc[j][3].y += g * pyy.y;
                    acc[j][4].x += g * pxy.x;  acc[j][4].y += g * pxy.y;
                }
            }
        }
#pragma unroll
        for (int j = 0; j < 4; ++j)
#pragma unroll
            for (int f = 0; f < 5; ++f)
                *(float2*)&hbuf[j][f][pws] = acc[j][f];
    }
    __syncthreads();

    lsum += hpass8(hbuf[row], l, win);    // no trailing barrier needed
    return lsum;
}

__global__ __launch_bounds__(256)
void ssim_quad2_kernel(const float* __restrict__ x,
                       const float* __restrict__ y,
                       double* __restrict__ accum,
                       GWin win)
{
    __shared__ __align__(16) float hbuf[4][5][PSTR];   // 42.24 KB
    __shared__ float wsum[4];

    const int tid   = threadIdx.x;
    const int band  = blockIdx.x & (BANDS - 1);
    const int plane = blockIdx.x >> 6;
    const int r0    = band * R_OUT;
    const int c0    = tid * 2;

    const float* __restrict__ xp = x + (size_t)plane * (IMG_H * IMG_W);
    const float* __restrict__ yp = y + (size_t)plane * (IMG_H * IMG_W);

    // zero halo cols: p in [0,8) and [520,528), 4 rows x 5 fields (swizzled slots)
    for (int i = tid; i < 320; i += 256) {
        int rf = i >> 4, w = i & 15;
        int p  = (w < 8) ? w : (512 + w);
        (&hbuf[0][0][0])[rf * PSTR + swzd(p)] = 0.f;
    }
    // (ordered before first h-read by the barrier inside quad_body)

    float lsum;
    if (band >= 1 && band <= BANDS - 2)
        lsum = quad_body<false>(xp, yp, r0, c0, tid, hbuf, win);
    else
        lsum = quad_body<true>(xp, yp, r0, c0, tid, hbuf, win);

    // block reduction
#pragma unroll
    for (int off = 32; off; off >>= 1) lsum += __shfl_down(lsum, off);
    if ((tid & 63) == 0) wsum[tid >> 6] = lsum;
    __syncthreads();
    if (tid == 0)
        atomicAdd(accum, (double)(wsum[0] + wsum[1] + wsum[2] + wsum[3]));
}

__global__ void ssim_finalize_kernel(const double* __restrict__ accum,
                                     float* __restrict__ out)
{
    out[0] = (float)(accum[0] / (double)TOTAL_PIX);
}

extern "C" void kernel_launch(void* const* d_in, const int* in_sizes, int n_in,
                              void* d_out, int out_size, void* d_ws, size_t ws_size,
                              hipStream_t stream) {
    const float* x = (const float*)d_in[0];
    const float* y = (const float*)d_in[1];
    float* out = (float*)d_out;
    double* accum = (double*)d_ws;

    GWin win;
    {
        double g[11], s = 0.0;
        for (int i = 0; i < 11; ++i) {
            double d = (double)i - 5.0;
            g[i] = std::exp(-(d * d) / (2.0 * 1.5 * 1.5));
            s += g[i];
        }
        for (int i = 0; i < 11; ++i) win.g[i] = (float)(g[i] / s);
    }

    hipMemsetAsync(d_ws, 0, sizeof(double), stream);

    const int nblocks = PLANES * BANDS;  // 3072
    ssim_quad2_kernel<<<nblocks, 256, 0, stream>>>(x, y, accum, win);
    ssim_finalize_kernel<<<1, 1, 0, stream>>>(accum, out);
}